// Round 13
// baseline (236.545 us; speedup 1.0000x reference)
//
#include <hip/hip_runtime.h>

#define D 128
#define NH 8
#define FOUT 16
#define NEG_SLOPE 0.2f
#define BN 96            // targets per bucket
#define NBK_MAX 1056
#define SCHUNK 8192      // edges per scatter block
#define CAP 3072         // max edges per bucket held in LDS

typedef __attribute__((ext_vector_type(8))) short bf16x8;
typedef __attribute__((ext_vector_type(4))) float f32x4;

__device__ __forceinline__ unsigned short f2bf(float x) {  // round-to-nearest-even
    unsigned u = __float_as_uint(x);
    return (unsigned short)((u + 0x7fffu + ((u >> 16) & 1u)) >> 16);
}

// ---- prep: pack W_src and wc (a_trg-folded W_trg) into MFMA B-fragment order (bf16)
__global__ __launch_bounds__(1024) void prep_kernel(
    const float* __restrict__ W_src, const float* __restrict__ W_trg,
    const float* __restrict__ a_trg,
    unsigned short* __restrict__ Wfrag, unsigned short* __restrict__ wcfrag) {
    __shared__ float wcs[NH][D];
    int t = threadIdx.x;
    {
        int h = t >> 7, d = t & 127;
        float acc = 0.f;
#pragma unroll
        for (int f = 0; f < FOUT; ++f)
            acc += a_trg[h * FOUT + f] * W_trg[(h * FOUT + f) * D + d];
        wcs[h][d] = acc;
    }
    __syncthreads();
    for (int o = t; o < D * D; o += 1024) {
        int j = o & 7, l = (o >> 3) & 63, c = (o >> 9) & 3, ntl = o >> 11;
        int col = ntl * 16 + (l & 15);
        int k = c * 32 + ((j >> 2) << 4) + (((l >> 4) & 3) << 2) + (j & 3);
        Wfrag[o] = f2bf(W_src[col * D + k]);
    }
    for (int o = t; o < 2048; o += 1024) {
        int j = o & 7, l = (o >> 3) & 63, c = o >> 9;
        int h = l & 15;
        int k = c * 32 + ((j >> 2) << 4) + (((l >> 4) & 3) << 2) + (j & 3);
        wcfrag[o] = (h < NH) ? f2bf(wcs[h][k]) : (unsigned short)0;
    }
}

// ---- MFMA projection (unchanged: pipelined staging, no global atomics)
__global__ __launch_bounds__(256) void proj_kernel(
    const float* __restrict__ src, const float* __restrict__ trg,
    const unsigned short* __restrict__ Wfrag, const unsigned short* __restrict__ wcfrag,
    const float* __restrict__ a_src,
    unsigned short* __restrict__ projb,
    float* __restrict__ s_src, float* __restrict__ s_trg,
    float* __restrict__ wmaxS, float* __restrict__ wmaxT, int N) {
    int tid = threadIdx.x;
    int lane = tid & 63;
    int w = tid >> 6;
    int cl = lane & 15, rq = lane >> 4;
    int n0 = blockIdx.x * 64;
    int nodes = min(64, N - n0);
    int nb0 = n0 + w * 16;

    __shared__ unsigned short tileS[64][132];
    __shared__ unsigned short tileT[64][132];

    const bf16x8* WF = (const bf16x8*)Wfrag;
    const bf16x8* WCF = (const bf16x8*)wcfrag;

    {
        const float4* s4 = (const float4*)src;
        const float4* t4 = (const float4*)trg;
        float4 vs[8], vt[8];
#pragma unroll
        for (int k = 0; k < 8; ++k) {
            int i = tid + k * 256;
            int r = i >> 5, c = i & 31;
            int rr = (r < nodes) ? r : (nodes - 1);
            size_t gi = (size_t)(n0 + rr) * 32 + c;
            vs[k] = s4[gi];
            vt[k] = t4[gi];
        }
#pragma unroll
        for (int k = 0; k < 8; ++k) {
            int i = tid + k * 256;
            int r = i >> 5, c = i & 31;
            ushort4 us, ut;
            us.x = f2bf(vs[k].x); us.y = f2bf(vs[k].y);
            us.z = f2bf(vs[k].z); us.w = f2bf(vs[k].w);
            ut.x = f2bf(vt[k].x); ut.y = f2bf(vt[k].y);
            ut.z = f2bf(vt[k].z); ut.w = f2bf(vt[k].w);
            *(ushort4*)&tileS[r][c * 4] = us;
            *(ushort4*)&tileT[r][c * 4] = ut;
        }
    }
    __syncthreads();

    f32x4 acc2 = {0.f, 0.f, 0.f, 0.f};
#pragma unroll
    for (int c = 0; c < 4; ++c) {
        const unsigned short* tp = &tileT[w * 16 + cl][c * 32 + rq * 4];
        union { unsigned long long q[2]; bf16x8 v; } af;
        af.q[0] = *(const unsigned long long*)tp;
        af.q[1] = *(const unsigned long long*)(tp + 16);
        acc2 = __builtin_amdgcn_mfma_f32_16x16x32_bf16(af.v, WCF[c * 64 + lane], acc2, 0, 0, 0);
    }

    union { unsigned long long q[2]; bf16x8 v; } af0, af1, af2, af3;
    {
        const unsigned short* tp = &tileS[w * 16 + cl][rq * 4];
        af0.q[0] = *(const unsigned long long*)tp;
        af0.q[1] = *(const unsigned long long*)(tp + 16);
        af1.q[0] = *(const unsigned long long*)(tp + 32);
        af1.q[1] = *(const unsigned long long*)(tp + 48);
        af2.q[0] = *(const unsigned long long*)(tp + 64);
        af2.q[1] = *(const unsigned long long*)(tp + 80);
        af3.q[0] = *(const unsigned long long*)(tp + 96);
        af3.q[1] = *(const unsigned long long*)(tp + 112);
    }
    f32x4 acc[8] = {{0.f,0.f,0.f,0.f},{0.f,0.f,0.f,0.f},{0.f,0.f,0.f,0.f},{0.f,0.f,0.f,0.f},
                    {0.f,0.f,0.f,0.f},{0.f,0.f,0.f,0.f},{0.f,0.f,0.f,0.f},{0.f,0.f,0.f,0.f}};
#pragma unroll
    for (int nt = 0; nt < 8; ++nt) {
        acc[nt] = __builtin_amdgcn_mfma_f32_16x16x32_bf16(af0.v, WF[(nt * 4 + 0) * 64 + lane], acc[nt], 0, 0, 0);
        acc[nt] = __builtin_amdgcn_mfma_f32_16x16x32_bf16(af1.v, WF[(nt * 4 + 1) * 64 + lane], acc[nt], 0, 0, 0);
        acc[nt] = __builtin_amdgcn_mfma_f32_16x16x32_bf16(af2.v, WF[(nt * 4 + 2) * 64 + lane], acc[nt], 0, 0, 0);
        acc[nt] = __builtin_amdgcn_mfma_f32_16x16x32_bf16(af3.v, WF[(nt * 4 + 3) * 64 + lane], acc[nt], 0, 0, 0);
    }

    float lmax = -1e30f, tmax = -1e30f;
#pragma unroll
    for (int i = 0; i < 4; ++i) {
        int node = nb0 + rq * 4 + i;
        if (cl < NH && node < N) {
            float dv = acc2[i];
            s_trg[(size_t)node * NH + cl] = dv;
            tmax = fmaxf(tmax, dv);
        }
    }
#pragma unroll
    for (int nt = 0; nt < 8; ++nt) {
        float av = a_src[nt * FOUT + cl];
#pragma unroll
        for (int i = 0; i < 4; ++i) {
            int node = nb0 + rq * 4 + i;
            float p = acc[nt][i] * av;
            p += __shfl_xor(p, 1); p += __shfl_xor(p, 2);
            p += __shfl_xor(p, 4); p += __shfl_xor(p, 8);
            if (node < N) {
                projb[(size_t)node * D + nt * 16 + cl] = f2bf(acc[nt][i]);
                if (cl == 0) s_src[(size_t)node * NH + nt] = p;
                lmax = fmaxf(lmax, p);
            }
        }
    }
#pragma unroll
    for (int off = 1; off < 64; off <<= 1) {
        lmax = fmaxf(lmax, __shfl_xor(lmax, off));
        tmax = fmaxf(tmax, __shfl_xor(tmax, off));
    }
    if (lane == 0) {
        wmaxS[blockIdx.x * 4 + w] = lmax;
        wmaxT[blockIdx.x * 4 + w] = tmax;
    }
}

// ---- coarse-bucket histogram (LDS per-block, merged)
__global__ void bhist_kernel(const int* __restrict__ ei, int* __restrict__ bcount,
                             int E, int nbk) {
    __shared__ int lh[NBK_MAX];
    for (int i = threadIdx.x; i < nbk; i += blockDim.x) lh[i] = 0;
    __syncthreads();
    for (int e = blockIdx.x * blockDim.x + threadIdx.x; e < E;
         e += gridDim.x * blockDim.x)
        atomicAdd(&lh[ei[E + e] / BN], 1);
    __syncthreads();
    for (int i = threadIdx.x; i < nbk; i += blockDim.x)
        if (lh[i]) atomicAdd(&bcount[i], lh[i]);
}

// ---- bucket scan (single block) + deterministic global max
__global__ void bscan_kernel(const int* __restrict__ bcount, int* __restrict__ bstart,
                             int* __restrict__ bcursor, int nbk,
                             const float* __restrict__ wmaxS,
                             const float* __restrict__ wmaxT, int nw,
                             float* __restrict__ gmaxf, int E) {
    __shared__ int tsum[256];
    __shared__ float r1[256], r2[256];
    int t = threadIdx.x;
    int per = (nbk + 255) >> 8;
    int s = 0;
    for (int k = 0; k < per; ++k) {
        int idx = t * per + k;
        if (idx < nbk) { bstart[idx] = s; s += bcount[idx]; }
    }
    tsum[t] = s;
    __syncthreads();
    for (int off = 1; off < 256; off <<= 1) {
        int x = (t >= off) ? tsum[t - off] : 0;
        __syncthreads();
        tsum[t] += x;
        __syncthreads();
    }
    int tpre = tsum[t] - s;
    for (int k = 0; k < per; ++k) {
        int idx = t * per + k;
        if (idx < nbk) { int v = bstart[idx] + tpre; bstart[idx] = v; bcursor[idx] = v; }
    }
    if (t == 0) bstart[nbk] = E;
    float m1 = -1e30f, m2 = -1e30f;
    for (int i = t; i < nw; i += 256) {
        m1 = fmaxf(m1, wmaxS[i]);
        m2 = fmaxf(m2, wmaxT[i]);
    }
    r1[t] = m1; r2[t] = m2;
    __syncthreads();
    for (int sft = 128; sft; sft >>= 1) {
        if (t < sft) { r1[t] = fmaxf(r1[t], r1[t + sft]); r2[t] = fmaxf(r2[t], r2[t + sft]); }
        __syncthreads();
    }
    if (t == 0) gmaxf[0] = r1[0] + r2[0];  // M >= true max; cancels in softmax
}

// ---- staged coarse scatter: LDS-reordered, run-coalesced writes
__global__ __launch_bounds__(256) void bscatter_kernel(
    const int* __restrict__ ei, int* __restrict__ bcursor,
    unsigned* __restrict__ bperm, int E, int nbk) {
    __shared__ unsigned words[SCHUNK];
    __shared__ unsigned short bks[SCHUNK];
    __shared__ int lh[NBK_MAX], lstart[NBK_MAX], gbase[NBK_MAX];
    __shared__ int tsum[256];
    int t = threadIdx.x;
    int e0 = blockIdx.x * SCHUNK;
    int m = min(SCHUNK, E - e0);

    for (int i = t; i < nbk; i += 256) lh[i] = 0;
    __syncthreads();
    for (int i = t; i < m; i += 256) atomicAdd(&lh[ei[E + e0 + i] / BN], 1);
    __syncthreads();
    int per = (nbk + 255) >> 8;
    int s = 0;
    for (int k = 0; k < per; ++k) {
        int idx = t * per + k;
        if (idx < nbk) { lstart[idx] = s; s += lh[idx]; }
    }
    tsum[t] = s;
    __syncthreads();
    for (int off = 1; off < 256; off <<= 1) {
        int x = (t >= off) ? tsum[t - off] : 0;
        __syncthreads();
        tsum[t] += x;
        __syncthreads();
    }
    int tpre = tsum[t] - s;
    for (int k = 0; k < per; ++k) {
        int idx = t * per + k;
        if (idx < nbk) lstart[idx] += tpre;
    }
    __syncthreads();
    for (int i = t; i < nbk; i += 256) {
        int c = lh[i];
        gbase[i] = c ? atomicAdd(&bcursor[i], c) : 0;
    }
    __syncthreads();
    for (int i = t; i < nbk; i += 256) lh[i] = 0;   // reuse as local cursor
    __syncthreads();
    for (int i = t; i < m; i += 256) {
        int si = ei[e0 + i], ti = ei[E + e0 + i];
        int bk = ti / BN, tl = ti - bk * BN;
        int lp = atomicAdd(&lh[bk], 1);
        int slot = lstart[bk] + lp;
        words[slot] = (unsigned)si | ((unsigned)tl << 17);
        bks[slot] = (unsigned short)bk;
    }
    __syncthreads();
    for (int i = t; i < m; i += 256) {
        int bk = bks[i];
        bperm[gbase[bk] + (i - lstart[bk])] = words[i];
    }
}

// ---- bucket aggregation: LDS counting-sort by target, wave-per-target register
//      accumulation, 4-way unrolled edge loop for memory-level parallelism
__global__ __launch_bounds__(256) void agg3_kernel(
    const int* __restrict__ bstart, const unsigned* __restrict__ bperm,
    const float* __restrict__ s_src, const float* __restrict__ s_trg,
    const unsigned short* __restrict__ projb, const float* __restrict__ gmaxf,
    float* __restrict__ out, int N) {
    int b = blockIdx.x;
    int t = threadIdx.x;
    int w = t >> 6, L = t & 63;
    int nbase = b * BN;
    int s0 = bstart[b], s1 = bstart[b + 1];
    int cnt = min(s1 - s0, CAP);

    __shared__ unsigned lsor[CAP];        // 12 KB
    __shared__ int tcnt[BN], toff[BN], tcur[BN];
    __shared__ float stg[BN * NH];        // 3 KB

    for (int i = t; i < BN; i += 256) tcnt[i] = 0;
    for (int i = t; i < BN * NH; i += 256) {
        int node = nbase + (i >> 3);
        stg[i] = (node < N) ? s_trg[(size_t)node * NH + (i & 7)] : 0.f;
    }
    __syncthreads();
    for (int i = t; i < cnt; i += 256) atomicAdd(&tcnt[bperm[s0 + i] >> 17], 1);
    __syncthreads();
    if (t == 0) {
        int s = 0;
        for (int k = 0; k < BN; ++k) { toff[k] = s; tcur[k] = s; s += tcnt[k]; }
    }
    __syncthreads();
    for (int i = t; i < cnt; i += 256) {
        unsigned wd = bperm[s0 + i];
        int p = atomicAdd(&tcur[wd >> 17], 1);
        lsor[p] = wd;
    }
    __syncthreads();

    float M = gmaxf[0];
    int h = L >> 3;
    const unsigned* p2 = (const unsigned*)projb;   // bf16x2, row stride 64

    for (int tl = w; tl < BN; tl += 4) {
        int node = nbase + tl;
        if (node >= N) continue;
        int e0 = toff[tl], ec = tcnt[tl];
        float acc0 = 0.f, acc1 = 0.f, wsum = 0.f;
        float sth = stg[tl * NH + h];
        int j = 0;
        for (; j + 3 < ec; j += 4) {
            unsigned wd0 = lsor[e0 + j],     wd1 = lsor[e0 + j + 1];
            unsigned wd2 = lsor[e0 + j + 2], wd3 = lsor[e0 + j + 3];
            int si0 = wd0 & 0x1FFFF, si1 = wd1 & 0x1FFFF;
            int si2 = wd2 & 0x1FFFF, si3 = wd3 & 0x1FFFF;
            // issue all 8 global loads before any consume
            float ss0 = s_src[(size_t)si0 * NH + h];
            float ss1 = s_src[(size_t)si1 * NH + h];
            float ss2 = s_src[(size_t)si2 * NH + h];
            float ss3 = s_src[(size_t)si3 * NH + h];
            unsigned pv0 = p2[(size_t)si0 * 64 + L];
            unsigned pv1 = p2[(size_t)si1 * 64 + L];
            unsigned pv2 = p2[(size_t)si2 * 64 + L];
            unsigned pv3 = p2[(size_t)si3 * 64 + L];
            float sc0 = ss0 + sth; sc0 = sc0 > 0.f ? sc0 : NEG_SLOPE * sc0;
            float sc1 = ss1 + sth; sc1 = sc1 > 0.f ? sc1 : NEG_SLOPE * sc1;
            float sc2 = ss2 + sth; sc2 = sc2 > 0.f ? sc2 : NEG_SLOPE * sc2;
            float sc3 = ss3 + sth; sc3 = sc3 > 0.f ? sc3 : NEG_SLOPE * sc3;
            float w0 = __expf(sc0 - M), w1 = __expf(sc1 - M);
            float w2 = __expf(sc2 - M), w3 = __expf(sc3 - M);
            wsum += (w0 + w1) + (w2 + w3);
            acc0 += w0 * __uint_as_float(pv0 << 16);
            acc1 += w0 * __uint_as_float(pv0 & 0xffff0000u);
            acc0 += w1 * __uint_as_float(pv1 << 16);
            acc1 += w1 * __uint_as_float(pv1 & 0xffff0000u);
            acc0 += w2 * __uint_as_float(pv2 << 16);
            acc1 += w2 * __uint_as_float(pv2 & 0xffff0000u);
            acc0 += w3 * __uint_as_float(pv3 << 16);
            acc1 += w3 * __uint_as_float(pv3 & 0xffff0000u);
        }
        for (; j < ec; ++j) {
            unsigned wd = lsor[e0 + j];
            int si = (int)(wd & 0x1FFFFu);
            float sc = s_src[(size_t)si * NH + h] + sth;
            sc = sc > 0.f ? sc : NEG_SLOPE * sc;
            float wgt = __expf(sc - M);
            unsigned pv = p2[(size_t)si * 64 + L];
            wsum += wgt;
            acc0 += wgt * __uint_as_float(pv << 16);
            acc1 += wgt * __uint_as_float(pv & 0xffff0000u);
        }
        float inv = 1.f / (wsum + 1e-16f);
        *((float2*)(out + (size_t)node * D + 2 * L)) = make_float2(acc0 * inv, acc1 * inv);
    }
}

extern "C" void kernel_launch(void* const* d_in, const int* in_sizes, int n_in,
                              void* d_out, int out_size, void* d_ws, size_t ws_size,
                              hipStream_t stream) {
    const float* trg   = (const float*)d_in[0];
    const float* src   = (const float*)d_in[1];
    const int*   ei    = (const int*)d_in[2];
    const float* W_trg = (const float*)d_in[3];
    const float* W_src = (const float*)d_in[4];
    const float* a_src = (const float*)d_in[5];
    const float* a_trg = (const float*)d_in[6];
    float* out = (float*)d_out;

    const int N = in_sizes[0] / D;   // 100000
    const int E = in_sizes[2] / 2;   // 1600000

    const int PB  = (N + 63) / 64;   // proj blocks
    const int NW  = PB * 4;          // per-wave max slots
    const int NBK = (N + BN - 1) / BN;   // 1042 buckets
    const int SCB = (E + SCHUNK - 1) / SCHUNK;  // 196 scatter blocks

    unsigned short* Wfrag  = (unsigned short*)d_ws;       // 16384 shorts (32 KB)
    unsigned short* wcfrag = Wfrag + D * D;               // 2048 shorts (4 KB)
    float* gmaxf    = (float*)(wcfrag + 2048);            // 1 (pad 4)
    float* wmaxS    = gmaxf + 4;                          // NW
    float* wmaxT    = wmaxS + NW;                         // NW
    float* s_src    = wmaxT + NW;                         // N*8
    float* s_trg    = s_src + (size_t)N * NH;             // N*8
    int*   bcount   = (int*)(s_trg + (size_t)N * NH);     // NBK
    int*   bstart   = bcount + NBK;                       // NBK+1
    int*   bcursor  = bstart + NBK + 1;                   // NBK
    unsigned* bperm = (unsigned*)(bcursor + NBK);         // E
    unsigned short* projb = (unsigned short*)(bperm + E); // N*128 bf16

    hipMemsetAsync(bcount, 0, (size_t)NBK * sizeof(int), stream);

    prep_kernel<<<1, 1024, 0, stream>>>(W_src, W_trg, a_trg, Wfrag, wcfrag);
    proj_kernel<<<PB, 256, 0, stream>>>(src, trg, Wfrag, wcfrag, a_src,
                                        projb, s_src, s_trg, wmaxS, wmaxT, N);
    bhist_kernel<<<512, 256, 0, stream>>>(ei, bcount, E, NBK);
    bscan_kernel<<<1, 256, 0, stream>>>(bcount, bstart, bcursor, NBK,
                                        wmaxS, wmaxT, NW, gmaxf, E);
    bscatter_kernel<<<SCB, 256, 0, stream>>>(ei, bcursor, bperm, E, NBK);
    agg3_kernel<<<NBK, 256, 0, stream>>>(bstart, bperm, s_src, s_trg,
                                         projb, gmaxf, out, N);
}

// Round 14
// 204.172 us; speedup vs baseline: 1.1586x; 1.1586x over previous
//
#include <hip/hip_runtime.h>

#define D 128
#define NH 8
#define FOUT 16
#define NEG_SLOPE 0.2f
#define BN 96            // targets per bucket
#define NBK_MAX 1056
#define SCHUNK 4096      // edges per scatter block (fused path)
#define CAP 3072         // fixed stride per bucket in bperm

typedef __attribute__((ext_vector_type(8))) short bf16x8;
typedef __attribute__((ext_vector_type(4))) float f32x4;

__device__ __forceinline__ unsigned short f2bf(float x) {  // round-to-nearest-even
    unsigned u = __float_as_uint(x);
    return (unsigned short)((u + 0x7fffu + ((u >> 16) & 1u)) >> 16);
}

// ---- prep: pack W_src and wc (a_trg-folded W_trg) into MFMA B-fragment order (bf16)
__global__ __launch_bounds__(1024) void prep_kernel(
    const float* __restrict__ W_src, const float* __restrict__ W_trg,
    const float* __restrict__ a_trg,
    unsigned short* __restrict__ Wfrag, unsigned short* __restrict__ wcfrag) {
    __shared__ float wcs[NH][D];
    int t = threadIdx.x;
    {
        int h = t >> 7, d = t & 127;
        float acc = 0.f;
#pragma unroll
        for (int f = 0; f < FOUT; ++f)
            acc += a_trg[h * FOUT + f] * W_trg[(h * FOUT + f) * D + d];
        wcs[h][d] = acc;
    }
    __syncthreads();
    for (int o = t; o < D * D; o += 1024) {
        int j = o & 7, l = (o >> 3) & 63, c = (o >> 9) & 3, ntl = o >> 11;
        int col = ntl * 16 + (l & 15);
        int k = c * 32 + ((j >> 2) << 4) + (((l >> 4) & 3) << 2) + (j & 3);
        Wfrag[o] = f2bf(W_src[col * D + k]);
    }
    for (int o = t; o < 2048; o += 1024) {
        int j = o & 7, l = (o >> 3) & 63, c = o >> 9;
        int h = l & 15;
        int k = c * 32 + ((j >> 2) << 4) + (((l >> 4) & 3) << 2) + (j & 3);
        wcfrag[o] = (h < NH) ? f2bf(wcs[h][k]) : (unsigned short)0;
    }
}

// ---- fused: blocks [0,PB): MFMA projection; blocks [PB,..): direct bucket scatter
__global__ __launch_bounds__(256) void projscat_kernel(
    const float* __restrict__ src, const float* __restrict__ trg,
    const unsigned short* __restrict__ Wfrag, const unsigned short* __restrict__ wcfrag,
    const float* __restrict__ a_src, const int* __restrict__ ei,
    unsigned short* __restrict__ projb,
    float* __restrict__ s_src, float* __restrict__ s_trg,
    float* __restrict__ wmaxS, float* __restrict__ wmaxT,
    int* __restrict__ bcnt, unsigned* __restrict__ bperm,
    int N, int E, int PB, int nbk) {
    __shared__ __align__(16) char shb[38400];   // overlaid LDS for both paths
    int tid = threadIdx.x;

    if (blockIdx.x >= PB) {
        // -------- scatter part: LDS-reorder, run-coalesced bucket append
        unsigned* words = (unsigned*)shb;                       // 4096
        unsigned short* bks = (unsigned short*)(shb + 16384);   // 4096
        int* lh     = (int*)(shb + 24576);
        int* lstart = (int*)(shb + 28800);
        int* gbase  = (int*)(shb + 33024);
        int* tsum   = (int*)(shb + 37248);
        int t = tid;
        int e0 = (blockIdx.x - PB) * SCHUNK;
        int m = min(SCHUNK, E - e0);
        if (m <= 0) return;

        for (int i = t; i < nbk; i += 256) lh[i] = 0;
        __syncthreads();
        for (int i = t; i < m; i += 256) atomicAdd(&lh[ei[E + e0 + i] / BN], 1);
        __syncthreads();
        int per = (nbk + 255) >> 8;
        int s = 0;
        for (int k = 0; k < per; ++k) {
            int idx = t * per + k;
            if (idx < nbk) { lstart[idx] = s; s += lh[idx]; }
        }
        tsum[t] = s;
        __syncthreads();
        for (int off = 1; off < 256; off <<= 1) {
            int x = (t >= off) ? tsum[t - off] : 0;
            __syncthreads();
            tsum[t] += x;
            __syncthreads();
        }
        int tpre = tsum[t] - s;
        for (int k = 0; k < per; ++k) {
            int idx = t * per + k;
            if (idx < nbk) lstart[idx] += tpre;
        }
        __syncthreads();
        for (int i = t; i < nbk; i += 256) {
            int c = lh[i];
            gbase[i] = c ? atomicAdd(&bcnt[i], c) : 0;
        }
        __syncthreads();
        for (int i = t; i < nbk; i += 256) lh[i] = 0;   // reuse as local cursor
        __syncthreads();
        for (int i = t; i < m; i += 256) {
            int si = ei[e0 + i], ti = ei[E + e0 + i];
            int bk = ti / BN, tl = ti - bk * BN;
            int lp = atomicAdd(&lh[bk], 1);
            int slot = lstart[bk] + lp;
            words[slot] = (unsigned)si | ((unsigned)tl << 17);
            bks[slot] = (unsigned short)bk;
        }
        __syncthreads();
        for (int i = t; i < m; i += 256) {
            int bk = bks[i];
            int pos = gbase[bk] + (i - lstart[bk]);
            if (pos < CAP) bperm[(size_t)bk * CAP + pos] = words[i];
        }
        return;
    }

    // -------- projection part (proven R10 structure)
    unsigned short (*tileS)[132] = (unsigned short(*)[132])shb;
    unsigned short (*tileT)[132] = (unsigned short(*)[132])(shb + 16896);
    int lane = tid & 63;
    int w = tid >> 6;
    int cl = lane & 15, rq = lane >> 4;
    int n0 = blockIdx.x * 64;
    int nodes = min(64, N - n0);
    int nb0 = n0 + w * 16;

    const bf16x8* WF = (const bf16x8*)Wfrag;
    const bf16x8* WCF = (const bf16x8*)wcfrag;

    {
        const float4* s4 = (const float4*)src;
        const float4* t4 = (const float4*)trg;
        float4 vs[8], vt[8];
#pragma unroll
        for (int k = 0; k < 8; ++k) {
            int i = tid + k * 256;
            int r = i >> 5, c = i & 31;
            int rr = (r < nodes) ? r : (nodes - 1);
            size_t gi = (size_t)(n0 + rr) * 32 + c;
            vs[k] = s4[gi];
            vt[k] = t4[gi];
        }
#pragma unroll
        for (int k = 0; k < 8; ++k) {
            int i = tid + k * 256;
            int r = i >> 5, c = i & 31;
            ushort4 us, ut;
            us.x = f2bf(vs[k].x); us.y = f2bf(vs[k].y);
            us.z = f2bf(vs[k].z); us.w = f2bf(vs[k].w);
            ut.x = f2bf(vt[k].x); ut.y = f2bf(vt[k].y);
            ut.z = f2bf(vt[k].z); ut.w = f2bf(vt[k].w);
            *(ushort4*)&tileS[r][c * 4] = us;
            *(ushort4*)&tileT[r][c * 4] = ut;
        }
    }
    __syncthreads();

    f32x4 acc2 = {0.f, 0.f, 0.f, 0.f};
#pragma unroll
    for (int c = 0; c < 4; ++c) {
        const unsigned short* tp = &tileT[w * 16 + cl][c * 32 + rq * 4];
        union { unsigned long long q[2]; bf16x8 v; } af;
        af.q[0] = *(const unsigned long long*)tp;
        af.q[1] = *(const unsigned long long*)(tp + 16);
        acc2 = __builtin_amdgcn_mfma_f32_16x16x32_bf16(af.v, WCF[c * 64 + lane], acc2, 0, 0, 0);
    }

    union { unsigned long long q[2]; bf16x8 v; } af0, af1, af2, af3;
    {
        const unsigned short* tp = &tileS[w * 16 + cl][rq * 4];
        af0.q[0] = *(const unsigned long long*)tp;
        af0.q[1] = *(const unsigned long long*)(tp + 16);
        af1.q[0] = *(const unsigned long long*)(tp + 32);
        af1.q[1] = *(const unsigned long long*)(tp + 48);
        af2.q[0] = *(const unsigned long long*)(tp + 64);
        af2.q[1] = *(const unsigned long long*)(tp + 80);
        af3.q[0] = *(const unsigned long long*)(tp + 96);
        af3.q[1] = *(const unsigned long long*)(tp + 112);
    }
    f32x4 acc[8] = {{0.f,0.f,0.f,0.f},{0.f,0.f,0.f,0.f},{0.f,0.f,0.f,0.f},{0.f,0.f,0.f,0.f},
                    {0.f,0.f,0.f,0.f},{0.f,0.f,0.f,0.f},{0.f,0.f,0.f,0.f},{0.f,0.f,0.f,0.f}};
#pragma unroll
    for (int nt = 0; nt < 8; ++nt) {
        acc[nt] = __builtin_amdgcn_mfma_f32_16x16x32_bf16(af0.v, WF[(nt * 4 + 0) * 64 + lane], acc[nt], 0, 0, 0);
        acc[nt] = __builtin_amdgcn_mfma_f32_16x16x32_bf16(af1.v, WF[(nt * 4 + 1) * 64 + lane], acc[nt], 0, 0, 0);
        acc[nt] = __builtin_amdgcn_mfma_f32_16x16x32_bf16(af2.v, WF[(nt * 4 + 2) * 64 + lane], acc[nt], 0, 0, 0);
        acc[nt] = __builtin_amdgcn_mfma_f32_16x16x32_bf16(af3.v, WF[(nt * 4 + 3) * 64 + lane], acc[nt], 0, 0, 0);
    }

    float lmax = -1e30f, tmax = -1e30f;
#pragma unroll
    for (int i = 0; i < 4; ++i) {
        int node = nb0 + rq * 4 + i;
        if (cl < NH && node < N) {
            float dv = acc2[i];
            s_trg[(size_t)node * NH + cl] = dv;
            tmax = fmaxf(tmax, dv);
        }
    }
#pragma unroll
    for (int nt = 0; nt < 8; ++nt) {
        float av = a_src[nt * FOUT + cl];
#pragma unroll
        for (int i = 0; i < 4; ++i) {
            int node = nb0 + rq * 4 + i;
            float p = acc[nt][i] * av;
            p += __shfl_xor(p, 1); p += __shfl_xor(p, 2);
            p += __shfl_xor(p, 4); p += __shfl_xor(p, 8);
            if (node < N) {
                projb[(size_t)node * D + nt * 16 + cl] = f2bf(acc[nt][i]);
                if (cl == 0) s_src[(size_t)node * NH + nt] = p;
                lmax = fmaxf(lmax, p);
            }
        }
    }
#pragma unroll
    for (int off = 1; off < 64; off <<= 1) {
        lmax = fmaxf(lmax, __shfl_xor(lmax, off));
        tmax = fmaxf(tmax, __shfl_xor(tmax, off));
    }
    if (lane == 0) {
        wmaxS[blockIdx.x * 4 + w] = lmax;
        wmaxT[blockIdx.x * 4 + w] = tmax;
    }
}

// ---- deterministic global max
__global__ void maxred_kernel(const float* __restrict__ wmaxS,
                              const float* __restrict__ wmaxT,
                              int nw, float* __restrict__ gmaxf) {
    __shared__ float r1[256], r2[256];
    int t = threadIdx.x;
    float m1 = -1e30f, m2 = -1e30f;
    for (int i = t; i < nw; i += 256) {
        m1 = fmaxf(m1, wmaxS[i]);
        m2 = fmaxf(m2, wmaxT[i]);
    }
    r1[t] = m1; r2[t] = m2;
    __syncthreads();
    for (int s = 128; s; s >>= 1) {
        if (t < s) { r1[t] = fmaxf(r1[t], r1[t + s]); r2[t] = fmaxf(r2[t], r2[t + s]); }
        __syncthreads();
    }
    if (t == 0) gmaxf[0] = r1[0] + r2[0];  // M >= true max; cancels in softmax
}

// ---- bucket aggregation: LDS counting-sort by target, wave-per-target register acc
__global__ __launch_bounds__(256) void agg3_kernel(
    const int* __restrict__ bcnt, const unsigned* __restrict__ bperm,
    const float* __restrict__ s_src, const float* __restrict__ s_trg,
    const unsigned short* __restrict__ projb, const float* __restrict__ gmaxf,
    float* __restrict__ out, int N) {
    int b = blockIdx.x;
    int t = threadIdx.x;
    int w = t >> 6, L = t & 63;
    int nbase = b * BN;
    int cnt = min(bcnt[b], CAP);
    const unsigned* bp = bperm + (size_t)b * CAP;

    __shared__ unsigned lsor[CAP];        // 12 KB
    __shared__ int tcnt[BN], toff[BN], tcur[BN];
    __shared__ float stg[BN * NH];        // 3 KB

    for (int i = t; i < BN; i += 256) tcnt[i] = 0;
    for (int i = t; i < BN * NH; i += 256) {
        int node = nbase + (i >> 3);
        stg[i] = (node < N) ? s_trg[(size_t)node * NH + (i & 7)] : 0.f;
    }
    __syncthreads();
    for (int i = t; i < cnt; i += 256) atomicAdd(&tcnt[bp[i] >> 17], 1);
    __syncthreads();
    if (t == 0) {
        int s = 0;
        for (int k = 0; k < BN; ++k) { toff[k] = s; tcur[k] = s; s += tcnt[k]; }
    }
    __syncthreads();
    for (int i = t; i < cnt; i += 256) {
        unsigned wd = bp[i];
        int p = atomicAdd(&tcur[wd >> 17], 1);
        lsor[p] = wd;
    }
    __syncthreads();

    float M = gmaxf[0];
    int h = L >> 3;
    const unsigned* p2 = (const unsigned*)projb;   // bf16x2, row stride 64

    for (int tl = w; tl < BN; tl += 4) {
        int node = nbase + tl;
        if (node >= N) continue;
        int e0 = toff[tl], ec = tcnt[tl];
        float acc0 = 0.f, acc1 = 0.f, wsum = 0.f;
        float sth = stg[tl * NH + h];
        for (int j = 0; j < ec; ++j) {
            unsigned wd = lsor[e0 + j];
            int si = (int)(wd & 0x1FFFFu);
            float sc = s_src[(size_t)si * NH + h] + sth;
            sc = sc > 0.f ? sc : NEG_SLOPE * sc;
            float wgt = __expf(sc - M);
            unsigned pv = p2[(size_t)si * 64 + L];
            wsum += wgt;
            acc0 += wgt * __uint_as_float(pv << 16);
            acc1 += wgt * __uint_as_float(pv & 0xffff0000u);
        }
        float inv = 1.f / (wsum + 1e-16f);
        *((float2*)(out + (size_t)node * D + 2 * L)) = make_float2(acc0 * inv, acc1 * inv);
    }
}

extern "C" void kernel_launch(void* const* d_in, const int* in_sizes, int n_in,
                              void* d_out, int out_size, void* d_ws, size_t ws_size,
                              hipStream_t stream) {
    const float* trg   = (const float*)d_in[0];
    const float* src   = (const float*)d_in[1];
    const int*   ei    = (const int*)d_in[2];
    const float* W_trg = (const float*)d_in[3];
    const float* W_src = (const float*)d_in[4];
    const float* a_src = (const float*)d_in[5];
    const float* a_trg = (const float*)d_in[6];
    float* out = (float*)d_out;

    const int N = in_sizes[0] / D;   // 100000
    const int E = in_sizes[2] / 2;   // 1600000

    const int PB  = (N + 63) / 64;               // proj blocks (1563)
    const int NW  = PB * 4;                      // per-wave max slots
    const int NBK = (N + BN - 1) / BN;           // 1042 buckets
    const int SCB = (E + SCHUNK - 1) / SCHUNK;   // 391 scatter blocks

    unsigned short* Wfrag  = (unsigned short*)d_ws;       // 16384 shorts (32 KB)
    unsigned short* wcfrag = Wfrag + D * D;               // 2048 shorts (4 KB)
    float* gmaxf    = (float*)(wcfrag + 2048);            // 1 (pad 4)
    float* wmaxS    = gmaxf + 4;                          // NW
    float* wmaxT    = wmaxS + NW;                         // NW
    float* s_src    = wmaxT + NW;                         // N*8
    float* s_trg    = s_src + (size_t)N * NH;             // N*8
    int*   bcnt     = (int*)(s_trg + (size_t)N * NH);     // NBK
    unsigned* bperm = (unsigned*)(bcnt + NBK);            // NBK*CAP (12.8 MB)
    unsigned short* projb = (unsigned short*)(bperm + (size_t)NBK * CAP);  // N*128 bf16

    hipMemsetAsync(bcnt, 0, (size_t)NBK * sizeof(int), stream);

    prep_kernel<<<1, 1024, 0, stream>>>(W_src, W_trg, a_trg, Wfrag, wcfrag);
    projscat_kernel<<<PB + SCB, 256, 0, stream>>>(
        src, trg, Wfrag, wcfrag, a_src, ei, projb, s_src, s_trg,
        wmaxS, wmaxT, bcnt, bperm, N, E, PB, NBK);
    maxred_kernel<<<1, 256, 0, stream>>>(wmaxS, wmaxT, NW, gmaxf);
    agg3_kernel<<<NBK, 256, 0, stream>>>(bcnt, bperm, s_src, s_trg,
                                         projb, gmaxf, out, N);
}